// Round 3
// baseline (192.279 us; speedup 1.0000x reference)
//
#include <hip/hip_runtime.h>

// ProtoNet forward: per (b,p) pair 16x64 sinkhorn (30 it, eps=0.1) + FFN head.
// Layout: one wave per pair. lane = ig*16 + jg (ig=0..3, jg=0..15).
// Lane owns rows i = ig + 4r (r=0..3) and cols j = jg + 16t (t=0..3).
// Iterations 1-2: log-domain (base-2). Iterations 3-30: stabilized
// multiplicative domain on E = 2^(F+G-Cb), re-absorbing u,v every 7 iters.
// All cross-lane reductions via DPP (quad_perm/row_ror) and permlane*_swap
// (full-rate VALU) instead of ds_bpermute-based __shfl_xor.

constexpr int   LMAX_ = 64, D_ = 128, PCS_ = 16;
constexpr float EPS_   = 0.1f;
constexpr float LOG2E_ = 1.4426950408889634f;
constexpr float SCALE_ = LOG2E_ / EPS_;          // C -> base-2/eps units
constexpr float LN2_   = 0.6931471805599453f;

#if __has_builtin(__builtin_amdgcn_exp2f)
__device__ __forceinline__ float exp2_(float x) { return __builtin_amdgcn_exp2f(x); }
#else
__device__ __forceinline__ float exp2_(float x) { return exp2f(x); }
#endif
#if __has_builtin(__builtin_amdgcn_log2f)
__device__ __forceinline__ float log2_(float x) { return __builtin_amdgcn_log2f(x); }
#else
__device__ __forceinline__ float log2_(float x) { return log2f(x); }
#endif
#if __has_builtin(__builtin_amdgcn_rcpf)
__device__ __forceinline__ float rcp_(float x) { return __builtin_amdgcn_rcpf(x); }
#else
__device__ __forceinline__ float rcp_(float x) { return 1.0f / x; }
#endif

// ---- DPP reduction helpers: jg axis = 16 contiguous lanes (one DPP row) ----
#if __has_builtin(__builtin_amdgcn_update_dpp)
template <int CTRL>
__device__ __forceinline__ float dpp_(float x) {
  return __int_as_float(__builtin_amdgcn_update_dpp(0, __float_as_int(x), CTRL, 0xF, 0xF, true));
}
__device__ __forceinline__ float rowsum16(float x) {
  x += dpp_<0xB1>(x);   // quad_perm [1,0,3,2] : xor1
  x += dpp_<0x4E>(x);   // quad_perm [2,3,0,1] : xor2
  x += dpp_<0x124>(x);  // row_ror:4 (quad-uniform by now -> valid)
  x += dpp_<0x128>(x);  // row_ror:8
  return x;
}
__device__ __forceinline__ float rowmax16(float x) {
  x = fmaxf(x, dpp_<0xB1>(x));
  x = fmaxf(x, dpp_<0x4E>(x));
  x = fmaxf(x, dpp_<0x124>(x));
  x = fmaxf(x, dpp_<0x128>(x));
  return x;
}
#else
__device__ __forceinline__ float rowsum16(float x) {
  x += __shfl_xor(x, 1); x += __shfl_xor(x, 2);
  x += __shfl_xor(x, 4); x += __shfl_xor(x, 8);
  return x;
}
__device__ __forceinline__ float rowmax16(float x) {
  x = fmaxf(x, __shfl_xor(x, 1)); x = fmaxf(x, __shfl_xor(x, 2));
  x = fmaxf(x, __shfl_xor(x, 4)); x = fmaxf(x, __shfl_xor(x, 8));
  return x;
}
#endif

// ---- ig axis (lane^16, lane^32) via permlane*_swap: ret0 op ret1 = x op x^k ----
#if __has_builtin(__builtin_amdgcn_permlane16_swap)
__device__ __forceinline__ float sum_x16(float x) {
  auto r = __builtin_amdgcn_permlane16_swap(__float_as_uint(x), __float_as_uint(x), false, false);
  return __uint_as_float(r[0]) + __uint_as_float(r[1]);
}
__device__ __forceinline__ float max_x16(float x) {
  auto r = __builtin_amdgcn_permlane16_swap(__float_as_uint(x), __float_as_uint(x), false, false);
  return fmaxf(__uint_as_float(r[0]), __uint_as_float(r[1]));
}
#else
__device__ __forceinline__ float sum_x16(float x) { return x + __shfl_xor(x, 16); }
__device__ __forceinline__ float max_x16(float x) { return fmaxf(x, __shfl_xor(x, 16)); }
#endif
#if __has_builtin(__builtin_amdgcn_permlane32_swap)
__device__ __forceinline__ float sum_x32(float x) {
  auto r = __builtin_amdgcn_permlane32_swap(__float_as_uint(x), __float_as_uint(x), false, false);
  return __uint_as_float(r[0]) + __uint_as_float(r[1]);
}
__device__ __forceinline__ float max_x32(float x) {
  auto r = __builtin_amdgcn_permlane32_swap(__float_as_uint(x), __float_as_uint(x), false, false);
  return fmaxf(__uint_as_float(r[0]), __uint_as_float(r[1]));
}
#else
__device__ __forceinline__ float sum_x32(float x) { return x + __shfl_xor(x, 32); }
__device__ __forceinline__ float max_x32(float x) { return fmaxf(x, __shfl_xor(x, 32)); }
#endif

__global__ __launch_bounds__(256, 5) void sink_fused(
    const float* __restrict__ atom_h,   // [512][64][128]
    const float* __restrict__ pc_X,     // [32][16][128]
    const int*   __restrict__ n_atoms,  // [512]
    float*       __restrict__ mol)      // [512][32] (ws)
{
  // [c4][row ^ (c4&7)] float4 layout: 32768 B exactly -> 5 blocks/CU.
  // Reads (fixed c4, lanes span 16 rows) are conflict-free; staging writes 4-way.
  __shared__ float4 Alds[2048];

  const int b    = blockIdx.x >> 3;                 // 8 blocks per molecule
  const int wave = threadIdx.x >> 6;
  const int pair = blockIdx.x * 4 + wave;           // = b*32 + p
  const int p    = pair & 31;
  const int lane = threadIdx.x & 63;
  const int ig   = lane >> 4;
  const int jg   = lane & 15;

  // ---- stage atom_h[b] into LDS (coalesced global reads) ----
  const float* Ag = atom_h + (size_t)b * (LMAX_ * D_);
  #pragma unroll
  for (int u = 0; u < 8; ++u) {
    int fidx = u * 256 + threadIdx.x;               // float4 index, 2048 total
    int row  = fidx >> 5;
    int c4   = fidx & 31;
    float4 v = *reinterpret_cast<const float4*>(Ag + row * D_ + c4 * 4);
    Alds[c4 * 64 + (row ^ (c4 & 7))] = v;
  }
  __syncthreads();

  const int    n  = n_atoms[b];
  const float* Xg = pc_X + (size_t)p * (PCS_ * D_);

  // ---- cost tile: Cb[r][t] = SCALE * (||x_i||^2 + ||a_j||^2 - 2 x_i.a_j) ----
  float acc[4][4], an[4], pn[4];
  #pragma unroll
  for (int r = 0; r < 4; ++r) { pn[r] = 0.f;
    #pragma unroll
    for (int t = 0; t < 4; ++t) acc[r][t] = 0.f; }
  #pragma unroll
  for (int t = 0; t < 4; ++t) an[t] = 0.f;

  #pragma unroll 2
  for (int c = 0; c < 32; ++c) {
    const int rsw = jg ^ (c & 7);
    const float4* Ab = &Alds[c * 64 + rsw];
    float4 at[4], px[4];
    at[0] = Ab[0]; at[1] = Ab[16]; at[2] = Ab[32]; at[3] = Ab[48];
    #pragma unroll
    for (int r = 0; r < 4; ++r)
      px[r] = *reinterpret_cast<const float4*>(Xg + (ig + 4 * r) * D_ + c * 4);
    #pragma unroll
    for (int r = 0; r < 4; ++r)
      #pragma unroll
      for (int t = 0; t < 4; ++t) {
        acc[r][t] = fmaf(px[r].x, at[t].x, acc[r][t]);
        acc[r][t] = fmaf(px[r].y, at[t].y, acc[r][t]);
        acc[r][t] = fmaf(px[r].z, at[t].z, acc[r][t]);
        acc[r][t] = fmaf(px[r].w, at[t].w, acc[r][t]);
      }
    #pragma unroll
    for (int t = 0; t < 4; ++t) {
      an[t] = fmaf(at[t].x, at[t].x, an[t]); an[t] = fmaf(at[t].y, at[t].y, an[t]);
      an[t] = fmaf(at[t].z, at[t].z, an[t]); an[t] = fmaf(at[t].w, at[t].w, an[t]);
    }
    #pragma unroll
    for (int r = 0; r < 4; ++r) {
      pn[r] = fmaf(px[r].x, px[r].x, pn[r]); pn[r] = fmaf(px[r].y, px[r].y, pn[r]);
      pn[r] = fmaf(px[r].z, px[r].z, pn[r]); pn[r] = fmaf(px[r].w, px[r].w, pn[r]);
    }
  }

  float Cb[4][4];
  #pragma unroll
  for (int r = 0; r < 4; ++r)
    #pragma unroll
    for (int t = 0; t < 4; ++t)
      Cb[r][t] = fmaf(-2.0f, acc[r][t], pn[r] + an[t]) * SCALE_;

  // ---- phase 1: 2 log-domain iterations (base-2 units) ----
  float lb2[4], G[4], F[4];
  const float lbv = -log2_((float)n);
  bool jv[4];
  #pragma unroll
  for (int t = 0; t < 4; ++t) {
    const int j = jg + 16 * t;
    jv[t]  = (j < n);
    lb2[t] = jv[t] ? lbv : -1.4426950e9f;    // log2e * NEG
    G[t]   = jv[t] ? 0.0f : -1e9f;           // padded cols contribute exactly 0 from it 1
  }

  #pragma unroll 1
  for (int it = 0; it < 2; ++it) {
    #pragma unroll
    for (int r = 0; r < 4; ++r) {
      float x0 = G[0] - Cb[r][0], x1 = G[1] - Cb[r][1];
      float x2 = G[2] - Cb[r][2], x3 = G[3] - Cb[r][3];
      float m = rowmax16(fmaxf(fmaxf(x0, x1), fmaxf(x2, x3)));
      float s = exp2_(x0 - m) + exp2_(x1 - m) + exp2_(x2 - m) + exp2_(x3 - m);
      s = rowsum16(s);
      F[r] = -4.0f - (m + log2_(s));
    }
    #pragma unroll
    for (int t = 0; t < 4; ++t) {
      float y0 = F[0] - Cb[0][t], y1 = F[1] - Cb[1][t];
      float y2 = F[2] - Cb[2][t], y3 = F[3] - Cb[3][t];
      float m = max_x32(max_x16(fmaxf(fmaxf(y0, y1), fmaxf(y2, y3))));
      float s = exp2_(y0 - m) + exp2_(y1 - m) + exp2_(y2 - m) + exp2_(y3 - m);
      s = sum_x32(sum_x16(s));
      G[t] = lb2[t] - (m + log2_(s));
    }
  }

  // ---- phase 2: 28 multiplicative iterations on E = 2^(F+G-Cb) ----
  // After a g-update, col sums of E are exactly b_j => entries <= 1/8.
  float E[4][4];
  #pragma unroll
  for (int r = 0; r < 4; ++r)
    #pragma unroll
    for (int t = 0; t < 4; ++t)
      E[r][t] = exp2_(F[r] + G[t] - Cb[r][t]);   // padded col -> exactly 0

  const float bn = 1.0f / (float)n;
  float u[4], v[4];

  #pragma unroll 1
  for (int blk = 0; blk < 4; ++blk) {            // 4 blocks x 7 iters = 28
    #pragma unroll 1
    for (int it = 0; it < 7; ++it) {
      // u_i = (1/16) / sum_j E_ij v_j   (first it of blk: v == 1)
      #pragma unroll
      for (int r = 0; r < 4; ++r) {
        float s;
        if (it == 0) {
          s = (E[r][0] + E[r][1]) + (E[r][2] + E[r][3]);
        } else {
          s = E[r][0] * v[0];
          s = fmaf(E[r][1], v[1], s);
          s = fmaf(E[r][2], v[2], s);
          s = fmaf(E[r][3], v[3], s);
        }
        s = rowsum16(s);
        u[r] = 0.0625f * rcp_(s);
      }
      // v_j = (1/n) / sum_i E_ij u_i ; padded col stays 0
      #pragma unroll
      for (int t = 0; t < 4; ++t) {
        float s = E[0][t] * u[0];
        s = fmaf(E[1][t], u[1], s);
        s = fmaf(E[2][t], u[2], s);
        s = fmaf(E[3][t], u[3], s);
        s = sum_x32(sum_x16(s));
        v[t] = jv[t] ? (bn * rcp_(s)) : 0.0f;
      }
    }
    // re-absorb u,v into E; resets u=v=1 for next block
    #pragma unroll
    for (int r = 0; r < 4; ++r) {
      #pragma unroll
      for (int t = 0; t < 4; ++t)
        E[r][t] *= u[r] * v[t];
    }
  }

  // ---- dist: after final absorb E == P. d = sum E*Cb (base-2 units) ----
  float d = 0.f;
  #pragma unroll
  for (int r = 0; r < 4; ++r)
    #pragma unroll
    for (int t = 0; t < 4; ++t)
      d = fmaf(E[r][t], Cb[r][t], d);
  d = sum_x32(sum_x16(rowsum16(d)));

  if (lane == 0) {
    // mol = -dist_nat * 16 * n / 100 ; dist_nat = d * eps * ln2 (Cb units -> nats)
    mol[pair] = -d * (EPS_ * LN2_ * 16.0f / 100.0f) * (float)n;
  }
}

__global__ __launch_bounds__(256) void ffn_head(
    const float* __restrict__ mol,  // [512][32]
    const float* __restrict__ W1,   // [32][256]
    const float* __restrict__ b1,   // [256]
    const float* __restrict__ W2,   // [256][1]
    const float* __restrict__ b2,   // [1]
    float*       __restrict__ out)  // [512]
{
  const int b = blockIdx.x;
  const int j = threadIdx.x;
  float m[32];
  #pragma unroll
  for (int k = 0; k < 32; ++k) m[k] = mol[b * 32 + k];
  float acc = b1[j];
  #pragma unroll
  for (int k = 0; k < 32; ++k) acc = fmaf(m[k], W1[k * 256 + j], acc);
  float v = fmaxf(acc, 0.0f) * W2[j];
  #pragma unroll
  for (int mask = 1; mask < 64; mask <<= 1) v += __shfl_xor(v, mask);
  __shared__ float red[4];
  if ((threadIdx.x & 63) == 0) red[threadIdx.x >> 6] = v;
  __syncthreads();
  if (threadIdx.x == 0) out[b] = red[0] + red[1] + red[2] + red[3] + b2[0];
}

extern "C" void kernel_launch(void* const* d_in, const int* in_sizes, int n_in,
                              void* d_out, int out_size, void* d_ws, size_t ws_size,
                              hipStream_t stream) {
  const float* atom_h = (const float*)d_in[0];
  const float* pc_X   = (const float*)d_in[1];
  const float* W1     = (const float*)d_in[2];
  const float* b1     = (const float*)d_in[3];
  const float* W2     = (const float*)d_in[4];
  const float* b2     = (const float*)d_in[5];
  const int*   n_at   = (const int*)d_in[6];

  float* mol = (float*)d_ws;           // 512*32*4 = 64 KB scratch
  float* out = (float*)d_out;          // [512] fp32

  sink_fused<<<4096, 256, 0, stream>>>(atom_h, pc_X, n_at, mol);
  ffn_head<<<512, 256, 0, stream>>>(mol, W1, b1, W2, b2, out);
}

// Round 4
// 180.811 us; speedup vs baseline: 1.0634x; 1.0634x over previous
//
#include <hip/hip_runtime.h>

// ProtoNet forward: per (b,p) pair 16x64 sinkhorn (30 it, eps=0.1) + FFN head.
// Layout: one wave per pair. lane = ig*16 + jg (ig=0..3, jg=0..15).
// Lane owns rows i = ig + 4r (r=0..3) and cols j = jg + 16t (t=0..3).
// Iterations 1-2: log-domain (base-2). Iterations 3-30: stabilized
// multiplicative domain on E = 2^(F+G-Cb), re-absorbing u,v every 7 iters.
// R4: packed-f32 (v_pk_fma_f32) for cost + mult phases; dual packed copies
// of E (ET: paired over t, ER: paired over r); cross-lane via __shfl_xor
// (DS pipe - runs parallel to the saturated VALU; R3 showed DPP regresses).

typedef float v2f __attribute__((ext_vector_type(2)));
struct alignas(16) f4v { v2f lo, hi; };

constexpr int   LMAX_ = 64, D_ = 128, PCS_ = 16;
constexpr float EPS_   = 0.1f;
constexpr float LOG2E_ = 1.4426950408889634f;
constexpr float SCALE_ = LOG2E_ / EPS_;          // C -> base-2/eps units
constexpr float LN2_   = 0.6931471805599453f;

#if __has_builtin(__builtin_amdgcn_exp2f)
__device__ __forceinline__ float exp2_(float x) { return __builtin_amdgcn_exp2f(x); }
#else
__device__ __forceinline__ float exp2_(float x) { return exp2f(x); }
#endif
#if __has_builtin(__builtin_amdgcn_log2f)
__device__ __forceinline__ float log2_(float x) { return __builtin_amdgcn_log2f(x); }
#else
__device__ __forceinline__ float log2_(float x) { return log2f(x); }
#endif
#if __has_builtin(__builtin_amdgcn_rcpf)
__device__ __forceinline__ float rcp_(float x) { return __builtin_amdgcn_rcpf(x); }
#else
__device__ __forceinline__ float rcp_(float x) { return 1.0f / x; }
#endif

__device__ __forceinline__ v2f fma2(v2f a, v2f b, v2f c) {
  return __builtin_elementwise_fma(a, b, c);
}
__device__ __forceinline__ v2f splat(float x) { v2f r; r.x = x; r.y = x; return r; }
__device__ __forceinline__ v2f shxor2(v2f x, int m) {
  v2f r; r.x = __shfl_xor(x.x, m); r.y = __shfl_xor(x.y, m); return r;
}

__global__ __launch_bounds__(256, 4) void sink_fused(
    const float* __restrict__ atom_h,   // [512][64][128]
    const float* __restrict__ pc_X,     // [32][16][128]
    const int*   __restrict__ n_atoms,  // [512]
    float*       __restrict__ mol)      // [512][32] (ws)
{
  // [c4][row ^ (c4&7)] f4v layout: 32768 B. Reads conflict-free.
  __shared__ f4v Alds[2048];

  const int b    = blockIdx.x >> 3;                 // 8 blocks per molecule
  const int wave = threadIdx.x >> 6;
  const int pair = blockIdx.x * 4 + wave;           // = b*32 + p
  const int p    = pair & 31;
  const int lane = threadIdx.x & 63;
  const int ig   = lane >> 4;
  const int jg   = lane & 15;

  // ---- stage atom_h[b] into LDS (coalesced global reads) ----
  const f4v* Ag = reinterpret_cast<const f4v*>(atom_h + (size_t)b * (LMAX_ * D_));
  #pragma unroll
  for (int u = 0; u < 8; ++u) {
    int fidx = u * 256 + threadIdx.x;               // float4 index, 2048 total
    int row  = fidx >> 5;
    int c4   = fidx & 31;
    Alds[c4 * 64 + (row ^ (c4 & 7))] = Ag[row * 32 + c4];
  }
  __syncthreads();

  const int  n  = n_atoms[b];
  const f4v* Xg = reinterpret_cast<const f4v*>(pc_X + (size_t)p * (PCS_ * D_));

  // ---- cost tile (packed): Cb[r][t] = SCALE*(||x||^2+||a||^2-2 x.a) ----
  v2f acc2[4][4], an2[4], pn2[4];
  #pragma unroll
  for (int r = 0; r < 4; ++r) { pn2[r] = splat(0.f);
    #pragma unroll
    for (int t = 0; t < 4; ++t) acc2[r][t] = splat(0.f); }
  #pragma unroll
  for (int t = 0; t < 4; ++t) an2[t] = splat(0.f);

  #pragma unroll 2
  for (int c = 0; c < 32; ++c) {
    const f4v* Ab = &Alds[c * 64 + (jg ^ (c & 7))];
    f4v at[4], px[4];
    at[0] = Ab[0]; at[1] = Ab[16]; at[2] = Ab[32]; at[3] = Ab[48];
    #pragma unroll
    for (int r = 0; r < 4; ++r)
      px[r] = Xg[(ig + 4 * r) * 32 + c];
    #pragma unroll
    for (int r = 0; r < 4; ++r)
      #pragma unroll
      for (int t = 0; t < 4; ++t) {
        acc2[r][t] = fma2(px[r].lo, at[t].lo, acc2[r][t]);
        acc2[r][t] = fma2(px[r].hi, at[t].hi, acc2[r][t]);
      }
    #pragma unroll
    for (int t = 0; t < 4; ++t) {
      an2[t] = fma2(at[t].lo, at[t].lo, an2[t]);
      an2[t] = fma2(at[t].hi, at[t].hi, an2[t]);
    }
    #pragma unroll
    for (int r = 0; r < 4; ++r) {
      pn2[r] = fma2(px[r].lo, px[r].lo, pn2[r]);
      pn2[r] = fma2(px[r].hi, px[r].hi, pn2[r]);
    }
  }

  float Cbs[4][4];
  #pragma unroll
  for (int r = 0; r < 4; ++r) {
    float pr = pn2[r].x + pn2[r].y;
    #pragma unroll
    for (int t = 0; t < 4; ++t)
      Cbs[r][t] = fmaf(-2.0f, acc2[r][t].x + acc2[r][t].y,
                       pr + (an2[t].x + an2[t].y)) * SCALE_;
  }

  // ---- phase 1: 2 log-domain iterations (base-2 units) ----
  float lb2[4], G[4], F[4];
  const float lbv = -log2_((float)n);
  bool jv[4];
  #pragma unroll
  for (int t = 0; t < 4; ++t) {
    const int j = jg + 16 * t;
    jv[t]  = (j < n);
    lb2[t] = jv[t] ? lbv : -1.4426950e9f;    // log2e * NEG
    G[t]   = jv[t] ? 0.0f : -1e9f;           // padded cols contribute exactly 0 from it 1
  }

  #pragma unroll 1
  for (int it = 0; it < 2; ++it) {
    #pragma unroll
    for (int r = 0; r < 4; ++r) {
      float x0 = G[0] - Cbs[r][0], x1 = G[1] - Cbs[r][1];
      float x2 = G[2] - Cbs[r][2], x3 = G[3] - Cbs[r][3];
      float m = fmaxf(fmaxf(x0, x1), fmaxf(x2, x3));
      m = fmaxf(m, __shfl_xor(m, 1));
      m = fmaxf(m, __shfl_xor(m, 2));
      m = fmaxf(m, __shfl_xor(m, 4));
      m = fmaxf(m, __shfl_xor(m, 8));
      float s = exp2_(x0 - m) + exp2_(x1 - m) + exp2_(x2 - m) + exp2_(x3 - m);
      s += __shfl_xor(s, 1);
      s += __shfl_xor(s, 2);
      s += __shfl_xor(s, 4);
      s += __shfl_xor(s, 8);
      F[r] = -4.0f - (m + log2_(s));
    }
    #pragma unroll
    for (int t = 0; t < 4; ++t) {
      float y0 = F[0] - Cbs[0][t], y1 = F[1] - Cbs[1][t];
      float y2 = F[2] - Cbs[2][t], y3 = F[3] - Cbs[3][t];
      float m = fmaxf(fmaxf(y0, y1), fmaxf(y2, y3));
      m = fmaxf(m, __shfl_xor(m, 16));
      m = fmaxf(m, __shfl_xor(m, 32));
      float s = exp2_(y0 - m) + exp2_(y1 - m) + exp2_(y2 - m) + exp2_(y3 - m);
      s += __shfl_xor(s, 16);
      s += __shfl_xor(s, 32);
      G[t] = lb2[t] - (m + log2_(s));
    }
  }

  // ---- phase 2: 28 multiplicative iterations on E = 2^(F+G-Cb) ----
  // Dual packed copies: ET[r][th] = (E[r][2th],E[r][2th+1]),
  //                     ER[rh][t] = (E[2rh][t],E[2rh+1][t]).
  float Ee[4][4];
  #pragma unroll
  for (int r = 0; r < 4; ++r)
    #pragma unroll
    for (int t = 0; t < 4; ++t)
      Ee[r][t] = exp2_(F[r] + G[t] - Cbs[r][t]);   // padded col -> exactly 0

  v2f ET[4][2], ER[2][4];
  #pragma unroll
  for (int r = 0; r < 4; ++r)
    #pragma unroll
    for (int h = 0; h < 2; ++h) { ET[r][h].x = Ee[r][2*h]; ET[r][h].y = Ee[r][2*h+1]; }
  #pragma unroll
  for (int h = 0; h < 2; ++h)
    #pragma unroll
    for (int t = 0; t < 4; ++t) { ER[h][t].x = Ee[2*h][t]; ER[h][t].y = Ee[2*h+1][t]; }

  const float bn = 1.0f / (float)n;
  float bm[4];
  #pragma unroll
  for (int t = 0; t < 4; ++t) bm[t] = jv[t] ? bn : 0.0f;

  float u[4], v[4];
  #pragma unroll
  for (int t = 0; t < 4; ++t) v[t] = 1.0f;       // identity after (re-)absorb

  const v2f tiny = splat(1e-30f);

  #pragma unroll 1
  for (int blk = 0; blk < 4; ++blk) {            // 4 blocks x 7 iters = 28
    #pragma unroll 1
    for (int it = 0; it < 7; ++it) {
      // u_i = (1/16) / sum_j E_ij v_j  -- pk over r-pairs (ER)
      v2f s01 = ER[0][0] * splat(v[0]);
      v2f s23 = ER[1][0] * splat(v[0]);
      s01 = fma2(ER[0][1], splat(v[1]), s01);
      s23 = fma2(ER[1][1], splat(v[1]), s23);
      s01 = fma2(ER[0][2], splat(v[2]), s01);
      s23 = fma2(ER[1][2], splat(v[2]), s23);
      s01 = fma2(ER[0][3], splat(v[3]), s01);
      s23 = fma2(ER[1][3], splat(v[3]), s23);
      s01 = s01 + shxor2(s01, 1);  s23 = s23 + shxor2(s23, 1);
      s01 = s01 + shxor2(s01, 2);  s23 = s23 + shxor2(s23, 2);
      s01 = s01 + shxor2(s01, 4);  s23 = s23 + shxor2(s23, 4);
      s01 = s01 + shxor2(s01, 8);  s23 = s23 + shxor2(s23, 8);
      u[0] = 0.0625f * rcp_(s01.x); u[1] = 0.0625f * rcp_(s01.y);
      u[2] = 0.0625f * rcp_(s23.x); u[3] = 0.0625f * rcp_(s23.y);

      // v_j = (1/n) / sum_i E_ij u_i  -- pk over t-pairs (ET)
      v2f T01 = ET[0][0] * splat(u[0]);
      v2f T23 = ET[0][1] * splat(u[0]);
      T01 = fma2(ET[1][0], splat(u[1]), T01);
      T23 = fma2(ET[1][1], splat(u[1]), T23);
      T01 = fma2(ET[2][0], splat(u[2]), T01);
      T23 = fma2(ET[2][1], splat(u[2]), T23);
      T01 = fma2(ET[3][0], splat(u[3]), T01);
      T23 = fma2(ET[3][1], splat(u[3]), T23);
      T01 = T01 + shxor2(T01, 16);  T23 = T23 + shxor2(T23, 16);
      T01 = T01 + shxor2(T01, 32);  T23 = T23 + shxor2(T23, 32);
      T01 = T01 + tiny;             T23 = T23 + tiny;
      v[0] = bm[0] * rcp_(T01.x); v[1] = bm[1] * rcp_(T01.y);
      v[2] = bm[2] * rcp_(T23.x); v[3] = bm[3] * rcp_(T23.y);
    }
    // re-absorb u,v into both packed copies; reset v to identity
    v2f vv01; vv01.x = v[0]; vv01.y = v[1];
    v2f vv23; vv23.x = v[2]; vv23.y = v[3];
    v2f uu01; uu01.x = u[0]; uu01.y = u[1];
    v2f uu23; uu23.x = u[2]; uu23.y = u[3];
    #pragma unroll
    for (int r = 0; r < 4; ++r) {
      ET[r][0] = ET[r][0] * (splat(u[r]) * vv01);
      ET[r][1] = ET[r][1] * (splat(u[r]) * vv23);
    }
    #pragma unroll
    for (int t = 0; t < 4; ++t) {
      ER[0][t] = ER[0][t] * (splat(v[t]) * uu01);
      ER[1][t] = ER[1][t] * (splat(v[t]) * uu23);
    }
    #pragma unroll
    for (int t = 0; t < 4; ++t) v[t] = 1.0f;
  }

  // ---- dist: after final absorb ET == P (packed by t). d = sum P*Cb ----
  v2f d2 = splat(0.f);
  #pragma unroll
  for (int r = 0; r < 4; ++r) {
    v2f cb0; cb0.x = Cbs[r][0]; cb0.y = Cbs[r][1];
    v2f cb1; cb1.x = Cbs[r][2]; cb1.y = Cbs[r][3];
    d2 = fma2(ET[r][0], cb0, d2);
    d2 = fma2(ET[r][1], cb1, d2);
  }
  float d = d2.x + d2.y;
  d += __shfl_xor(d, 1);
  d += __shfl_xor(d, 2);
  d += __shfl_xor(d, 4);
  d += __shfl_xor(d, 8);
  d += __shfl_xor(d, 16);
  d += __shfl_xor(d, 32);

  if (lane == 0) {
    // mol = -dist_nat * 16 * n / 100 ; dist_nat = d * eps * ln2 (Cb units -> nats)
    mol[pair] = -d * (EPS_ * LN2_ * 16.0f / 100.0f) * (float)n;
  }
}

__global__ __launch_bounds__(256) void ffn_head(
    const float* __restrict__ mol,  // [512][32]
    const float* __restrict__ W1,   // [32][256]
    const float* __restrict__ b1,   // [256]
    const float* __restrict__ W2,   // [256][1]
    const float* __restrict__ b2,   // [1]
    float*       __restrict__ out)  // [512]
{
  const int b = blockIdx.x;
  const int j = threadIdx.x;
  float m[32];
  #pragma unroll
  for (int k = 0; k < 32; ++k) m[k] = mol[b * 32 + k];
  float acc = b1[j];
  #pragma unroll
  for (int k = 0; k < 32; ++k) acc = fmaf(m[k], W1[k * 256 + j], acc);
  float v = fmaxf(acc, 0.0f) * W2[j];
  #pragma unroll
  for (int mask = 1; mask < 64; mask <<= 1) v += __shfl_xor(v, mask);
  __shared__ float red[4];
  if ((threadIdx.x & 63) == 0) red[threadIdx.x >> 6] = v;
  __syncthreads();
  if (threadIdx.x == 0) out[b] = red[0] + red[1] + red[2] + red[3] + b2[0];
}

extern "C" void kernel_launch(void* const* d_in, const int* in_sizes, int n_in,
                              void* d_out, int out_size, void* d_ws, size_t ws_size,
                              hipStream_t stream) {
  const float* atom_h = (const float*)d_in[0];
  const float* pc_X   = (const float*)d_in[1];
  const float* W1     = (const float*)d_in[2];
  const float* b1     = (const float*)d_in[3];
  const float* W2     = (const float*)d_in[4];
  const float* b2     = (const float*)d_in[5];
  const int*   n_at   = (const int*)d_in[6];

  float* mol = (float*)d_ws;           // 512*32*4 = 64 KB scratch
  float* out = (float*)d_out;          // [512] fp32

  sink_fused<<<4096, 256, 0, stream>>>(atom_h, pc_X, n_at, mol);
  ffn_head<<<512, 256, 0, stream>>>(mol, W1, b1, W2, b2, out);
}